// Round 6
// baseline (100.239 us; speedup 1.0000x reference)
//
#include <hip/hip_runtime.h>

#define NVAR   576
#define NROW   144
#define DEG    15
#define NEDGE  (NROW * DEG)   // 2160
#define NBATCH 256
#define NITER  3
#define NT     192            // 3 waves; t<144 owns a row in the decode phase
#define NWORD  9              // 576 bits = 9 x 64-bit words per row
#define NWTOT  (NROW * NWORD) // 1296 bitmask words
#define WPW    (NWTOT / 3)    // 432 words per wave

// Single fused kernel, one block per batch element.
// Phase 1 (chain-free, unlike the R4 fusion that regressed): each of the 3
//   waves converts 432 independent 64-column chunks of H into bitmask words
//   (coalesced 256B load -> ballot -> lane0 LDS store), unrolled x8 for MLP.
//   H is 331 KB -> L2/L3-resident across the 256 blocks.
// Phase 2: per-row ffs extraction of the 15 column indices (ascending order
//   -> matches top_k lowest-index tie-breaking), then the proven
//   register-resident min-sum decode (thread t<144 owns row t: cols, M, E,
//   r@cols all in registers; LDS holds rs + ping-pong column accumulators).
__launch_bounds__(NT, 1)
__global__ void ldpc_fused_kernel(const float* __restrict__ r,
                                  const float* __restrict__ H,
                                  const float* __restrict__ alpha,
                                  const float* __restrict__ beta,
                                  float* __restrict__ out) {
    __shared__ unsigned long long bitw[NWTOT];  // 10368 B
    __shared__ float rs[NVAR];
    __shared__ float sA[NVAR];                  // ping-pong column accumulators
    __shared__ float sB[NVAR];
    __shared__ short colsh[NROW * 16];          // row stride padded to 16

    const int b    = blockIdx.x;
    const int t    = threadIdx.x;
    const int wv   = t >> 6;                    // wave id 0..2
    const int lane = t & 63;

    float alr[NITER], ber[NITER];
    #pragma unroll
    for (int i = 0; i < NITER; ++i) { alr[i] = alpha[i]; ber[i] = beta[i]; }

    // Stage r (coalesced) + zero first accumulator; latency hides under phase 1.
    #pragma unroll
    for (int k = 0; k < 3; ++k) {
        int n = t + k * NT;
        rs[n] = r[b * NVAR + n];
        sA[n] = 0.0f;
    }

    // Phase 1: H -> bitmask words. No cross-iteration dependency; x8 unroll
    // keeps 8 loads in flight per wave.
    {
        const int base = wv * WPW;
        for (int i = 0; i < WPW; i += 8) {
            float h[8];
            #pragma unroll
            for (int u = 0; u < 8; ++u)
                h[u] = H[(base + i + u) * 64 + lane];
            #pragma unroll
            for (int u = 0; u < 8; ++u) {
                unsigned long long m = __ballot(h[u] != 0.0f);
                if (lane == 0) bitw[base + i + u] = m;
            }
        }
    }
    __syncthreads();   // bitw + rs ready

    // Phase 2a: extract this row's 15 column indices from its 9 LDS words.
    if (t < NROW) {
        int k = 0;
        #pragma unroll
        for (int i = 0; i < NWORD; ++i) {
            unsigned long long bw = bitw[t * NWORD + i];
            while (bw) {
                int p = __ffsll((long long)bw) - 1;
                bw &= bw - 1;
                colsh[t * 16 + k] = (short)(i * 64 + p);  // dynamic k -> LDS
                ++k;
            }
        }
    }
    __syncthreads();

    // Phase 2b: row-owned register state.
    int   ci[DEG];
    float Mv[DEG], Ev[DEG], rc[DEG];
    if (t < NROW) {
        #pragma unroll
        for (int j = 0; j < DEG; ++j) ci[j] = (int)colsh[t * 16 + j];
        #pragma unroll
        for (int j = 0; j < DEG; ++j) { rc[j] = rs[ci[j]]; Mv[j] = rc[j]; }
    }

    #pragma unroll
    for (int it = 0; it < NITER; ++it) {
        float* sum = (it & 1) ? sB : sA;   // scatter target (pre-zeroed)
        float* nxt = (it & 1) ? sA : sB;   // zeroed this iter for next scatter

        if (t < NROW) {
            // In-register min1/min2/argmin/sign-parity reduce over 15 edges.
            float m1 = INFINITY, m2 = INFINITY, sg = 1.0f;
            int j1 = 0;
            #pragma unroll
            for (int j = 0; j < DEG; ++j) {
                float v = Mv[j];
                float a = fabsf(v);
                float s = (v > 0.0f) ? 1.0f : ((v < 0.0f) ? -1.0f : 0.0f);
                sg *= s;
                if (a < m1) { m2 = m1; m1 = a; j1 = j; }
                else if (a < m2) { m2 = a; }
            }
            // E values + column scatter (E stays in registers).
            #pragma unroll
            for (int j = 0; j < DEG; ++j) {
                float v = Mv[j];
                float s = (v > 0.0f) ? 1.0f : ((v < 0.0f) ? -1.0f : 0.0f);
                float eabs = (j == j1) ? m2 : m1;
                float e = alr[it] * sg * s * fmaxf(0.0f, eabs - ber[it]);
                Ev[j] = e;
                atomicAdd(&sum[ci[j]], e);
            }
        }
        __syncthreads();   // drain scatter

        if (it == NITER - 1) {
            #pragma unroll
            for (int k = 0; k < 3; ++k) {
                int n = t + k * NT;
                out[b * NVAR + n] = rs[n] + sum[n];
            }
        } else {
            // Zero the other buffer for the next iteration (disjoint from sum).
            #pragma unroll
            for (int k = 0; k < 3; ++k) nxt[t + k * NT] = 0.0f;
            // In-register M update: M = r + sumE - E at this row's columns.
            if (t < NROW) {
                #pragma unroll
                for (int j = 0; j < DEG; ++j)
                    Mv[j] = rc[j] + sum[ci[j]] - Ev[j];
            }
            __syncthreads();
        }
    }
}

extern "C" void kernel_launch(void* const* d_in, const int* in_sizes, int n_in,
                              void* d_out, int out_size, void* d_ws, size_t ws_size,
                              hipStream_t stream) {
    const float* r     = (const float*)d_in[0];
    const float* H     = (const float*)d_in[1];
    const float* alpha = (const float*)d_in[2];
    const float* beta  = (const float*)d_in[3];
    float* out = (float*)d_out;
    (void)d_ws; (void)ws_size;

    ldpc_fused_kernel<<<NBATCH, NT, 0, stream>>>(r, H, alpha, beta, out);
}

// Round 7
// 86.665 us; speedup vs baseline: 1.1566x; 1.1566x over previous
//
#include <hip/hip_runtime.h>

#define NVAR    576
#define NROW    144
#define DEG     15
#define NITER   3
#define NWORD   9                    // 576 bits = 9 x 64-bit words per row
#define NWTOT   (NROW * NWORD)       // 1296
#define MAXD    16                   // max column degree supported (actual ~12)
#define ESTRIDE 17                   // E_lds row stride; 17 coprime 32 -> no bank conflicts
#define EZERO   (143 * ESTRIDE + DEG - 1 + 1)   // 2446: sentinel slot, always 0.0f
#define ESIZE   (EZERO + 2)          // 2448 floats
#define NT      192                  // decode block: 3 waves

// ---------------- K1: H -> per-row bitmask words (chain-free, proven R5) ----
__global__ void build_bits_kernel(const float* __restrict__ H,
                                  unsigned long long* __restrict__ bits) {
    int gid  = blockIdx.x * blockDim.x + threadIdx.x;
    int wid  = gid >> 6;
    int lane = gid & 63;
    if (wid >= NWTOT) return;
    float h = H[wid * 64 + lane];
    unsigned long long m = __ballot(h != 0.0f);
    if (lane == 0) bits[wid] = m;
}

// ---------------- K2: bitmask -> CSR cols + CSC edge lists (1 block) --------
// cols_rows[m*16+j] = column of row m's j-th edge (ascending -> top_k parity).
// csc[n*16+d]       = E_lds address (row*ESTRIDE+j) of column n's d-th edge,
//                     padded with EZERO so decode can do 16 unconditional adds.
__launch_bounds__(576, 1)
__global__ void build_csc_kernel(const unsigned long long* __restrict__ bits,
                                 unsigned short* __restrict__ cols_rows,
                                 unsigned short* __restrict__ csc) {
    __shared__ unsigned long long bitw[NWTOT];
    __shared__ int pf[NROW * NWORD];            // exclusive word-prefix popcounts

    const int t = threadIdx.x;
    for (int i = t; i < NWTOT; i += 576) bitw[i] = bits[i];
    __syncthreads();

    if (t < NROW) {
        int acc = 0;
        #pragma unroll
        for (int w = 0; w < NWORD; ++w) {
            pf[t * NWORD + w] = acc;
            acc += __popcll(bitw[t * NWORD + w]);
        }
    }
    __syncthreads();

    // Column scan: thread t owns column t. Word reads are wave-uniform
    // (broadcast); bit tests are per-lane.
    const int wsel = t >> 6, bitpos = t & 63;
    int deg = 0;
    for (int m = 0; m < NROW; ++m) {
        unsigned long long word = bitw[m * NWORD + wsel];
        if ((word >> bitpos) & 1ull) {
            int j = pf[m * NWORD + wsel]
                  + (int)__popcll(word & ((1ull << bitpos) - 1ull));
            if (deg < MAXD) csc[t * MAXD + deg] = (unsigned short)(m * ESTRIDE + j);
            ++deg;
            cols_rows[m * 16 + j] = (unsigned short)t;
        }
    }
    for (int d = deg; d < MAXD; ++d) csc[t * MAXD + d] = (unsigned short)EZERO;
}

// ---------------- K3: decode, zero atomics --------------------------------
// Thread t<144 owns row t (cols/M/E/r@cols in registers); all 192 threads own
// 3 columns each for the gather. E scatter -> conflict-free LDS writes
// (stride 17); column sums -> pure LDS gather reads via CSC.
__launch_bounds__(NT, 1)
__global__ void ldpc_decode_kernel(const float* __restrict__ r,
                                   const unsigned short* __restrict__ cols_rows,
                                   const unsigned short* __restrict__ csc,
                                   const float* __restrict__ alpha,
                                   const float* __restrict__ beta,
                                   float* __restrict__ out) {
    __shared__ float rs[NVAR];
    __shared__ float Elds[ESIZE];
    __shared__ float sumE[NVAR];

    const int b = blockIdx.x;
    const int t = threadIdx.x;

    float alr[NITER], ber[NITER];
    #pragma unroll
    for (int i = 0; i < NITER; ++i) { alr[i] = alpha[i]; ber[i] = beta[i]; }

    // Stage r (coalesced); zero the gather sentinel.
    #pragma unroll
    for (int k = 0; k < 3; ++k) rs[t + k * NT] = r[b * NVAR + t + k * NT];
    if (t == 0) { Elds[EZERO] = 0.0f; Elds[EZERO + 1] = 0.0f; }

    // My 3 columns' CSC entries (two uint4 = 16 padded ushorts each).
    unsigned int cw[3][8];
    #pragma unroll
    for (int k = 0; k < 3; ++k) {
        const uint4* p = (const uint4*)(csc + (t + k * NT) * MAXD);
        uint4 a = p[0], c = p[1];
        cw[k][0] = a.x; cw[k][1] = a.y; cw[k][2] = a.z; cw[k][3] = a.w;
        cw[k][4] = c.x; cw[k][5] = c.y; cw[k][6] = c.z; cw[k][7] = c.w;
    }

    // My row's 15 column indices (two uint4 = 16 ushorts, entry 15 unused).
    int ci[DEG];
    if (t < NROW) {
        const uint4* p = (const uint4*)(cols_rows + t * 16);
        uint4 a = p[0], c = p[1];
        unsigned int uw[8] = {a.x, a.y, a.z, a.w, c.x, c.y, c.z, c.w};
        #pragma unroll
        for (int j = 0; j < DEG; ++j)
            ci[j] = (int)((uw[j >> 1] >> ((j & 1) * 16)) & 0xffffu);
    }
    __syncthreads();   // rs + sentinel ready

    float Mv[DEG], Ev[DEG], rc[DEG];
    if (t < NROW) {
        #pragma unroll
        for (int j = 0; j < DEG; ++j) { rc[j] = rs[ci[j]]; Mv[j] = rc[j]; }
    }

    #pragma unroll
    for (int it = 0; it < NITER; ++it) {
        if (t < NROW) {
            // In-register min1/min2/argmin/sign-parity reduce over 15 edges.
            float m1 = INFINITY, m2 = INFINITY, sg = 1.0f;
            int j1 = 0;
            #pragma unroll
            for (int j = 0; j < DEG; ++j) {
                float v = Mv[j];
                float a = fabsf(v);
                float s = (v > 0.0f) ? 1.0f : ((v < 0.0f) ? -1.0f : 0.0f);
                sg *= s;
                if (a < m1) { m2 = m1; m1 = a; j1 = j; }
                else if (a < m2) { m2 = a; }
            }
            // E values -> registers + conflict-free LDS scatter (stride 17).
            #pragma unroll
            for (int j = 0; j < DEG; ++j) {
                float v = Mv[j];
                float s = (v > 0.0f) ? 1.0f : ((v < 0.0f) ? -1.0f : 0.0f);
                float eabs = (j == j1) ? m2 : m1;
                float e = alr[it] * sg * s * fmaxf(0.0f, eabs - ber[it]);
                Ev[j] = e;
                Elds[t * ESTRIDE + j] = e;
            }
        }
        __syncthreads();   // E ready

        // Column gather: 16 unconditional adds per column (sentinel -> +0).
        #pragma unroll
        for (int k = 0; k < 3; ++k) {
            float s = 0.0f;
            #pragma unroll
            for (int d = 0; d < MAXD; ++d)
                s += Elds[(cw[k][d >> 1] >> ((d & 1) * 16)) & 0xffffu];
            int n = t + k * NT;
            if (it == NITER - 1) out[b * NVAR + n] = rs[n] + s;
            else                 sumE[n] = s;
        }

        if (it < NITER - 1) {
            __syncthreads();   // sumE ready; also guards next iter's E writes
            if (t < NROW) {
                #pragma unroll
                for (int j = 0; j < DEG; ++j)
                    Mv[j] = rc[j] + sumE[ci[j]] - Ev[j];
            }
        }
    }
}

extern "C" void kernel_launch(void* const* d_in, const int* in_sizes, int n_in,
                              void* d_out, int out_size, void* d_ws, size_t ws_size,
                              hipStream_t stream) {
    const float* r     = (const float*)d_in[0];
    const float* H     = (const float*)d_in[1];
    const float* alpha = (const float*)d_in[2];
    const float* beta  = (const float*)d_in[3];
    float* out = (float*)d_out;

    // ws layout (all 16B-aligned): bits 10368 B | cols_rows 4608 B | csc 18432 B
    unsigned long long* bits      = (unsigned long long*)d_ws;
    unsigned short*     cols_rows = (unsigned short*)((char*)d_ws + 10368);
    unsigned short*     csc       = (unsigned short*)((char*)d_ws + 14976);

    build_bits_kernel<<<(NWTOT * 64 + 255) / 256, 256, 0, stream>>>(H, bits);
    build_csc_kernel<<<1, 576, 0, stream>>>(bits, cols_rows, csc);
    ldpc_decode_kernel<<<256, NT, 0, stream>>>(r, cols_rows, csc, alpha, beta, out);
}